// Round 1
// baseline (731.961 us; speedup 1.0000x reference)
//
#include <hip/hip_runtime.h>

#define NFEAT 128
#define NHID  64
#define NOUT  21

// ---------------- degree / norm ----------------

__global__ __launch_bounds__(256) void k_deg_init(float* deg, int N) {
    int i = blockIdx.x * 256 + threadIdx.x;
    if (i < N) deg[i] = 1.0f;  // self-loop
}

__global__ __launch_bounds__(256) void k_deg_edges(const int* __restrict__ dst, float* deg, int E) {
    int e = blockIdx.x * 256 + threadIdx.x;
    if (e < E) atomicAdd(&deg[dst[e]], 1.0f);
}

__global__ __launch_bounds__(256) void k_dinv(float* deg, int N) {
    int i = blockIdx.x * 256 + threadIdx.x;
    if (i < N) deg[i] = rsqrtf(deg[i]);  // deg >= 1 always
}

__global__ __launch_bounds__(256) void k_norm(const int* __restrict__ src, const int* __restrict__ dst,
                                              const float* __restrict__ dinv, float* __restrict__ nrm, int E) {
    int e = blockIdx.x * 256 + threadIdx.x;
    if (e < E) nrm[e] = dinv[src[e]] * dinv[dst[e]];
}

// ---------------- GEMM1: h = x @ W1  [N,128]x[128,64] ----------------
// Block = 256 threads = 64 rows x 4 col-groups of 16. W1 (32KB) in LDS,
// uniform-ish broadcast reads; x via float4 (4 lanes share a row -> broadcast).

__global__ __launch_bounds__(256) void k_gemm1(const float* __restrict__ x, const float* __restrict__ W1,
                                               float* __restrict__ h, int N) {
    __shared__ float Ws[NFEAT * NHID];  // 32 KB
    int tid = threadIdx.x;
#pragma unroll
    for (int i = 0; i < 8; ++i) {
        int idx = (tid + i * 256) * 4;
        *(float4*)&Ws[idx] = *(const float4*)&W1[idx];
    }
    __syncthreads();
    int row = blockIdx.x * 64 + (tid >> 2);
    if (row >= N) return;
    int cg = (tid & 3) * 16;
    float acc[16];
#pragma unroll
    for (int j = 0; j < 16; ++j) acc[j] = 0.f;
    const float* xr = x + (size_t)row * NFEAT;
#pragma unroll 4
    for (int k4 = 0; k4 < NFEAT / 4; ++k4) {
        float4 xv = *(const float4*)&xr[k4 * 4];
        float xs[4] = {xv.x, xv.y, xv.z, xv.w};
#pragma unroll
        for (int kk = 0; kk < 4; ++kk) {
            const float* wrow = &Ws[(k4 * 4 + kk) * NHID + cg];
#pragma unroll
            for (int j4 = 0; j4 < 4; ++j4) {
                float4 w = *(const float4*)&wrow[j4 * 4];
                acc[j4 * 4 + 0] = fmaf(xs[kk], w.x, acc[j4 * 4 + 0]);
                acc[j4 * 4 + 1] = fmaf(xs[kk], w.y, acc[j4 * 4 + 1]);
                acc[j4 * 4 + 2] = fmaf(xs[kk], w.z, acc[j4 * 4 + 2]);
                acc[j4 * 4 + 3] = fmaf(xs[kk], w.w, acc[j4 * 4 + 3]);
            }
        }
    }
    float* hr = h + (size_t)row * NHID + cg;
#pragma unroll
    for (int j4 = 0; j4 < 4; ++j4)
        *(float4*)&hr[j4 * 4] = make_float4(acc[j4 * 4 + 0], acc[j4 * 4 + 1],
                                            acc[j4 * 4 + 2], acc[j4 * 4 + 3]);
}

// ---------------- aggregation layer 1 (64 feat) ----------------

__global__ __launch_bounds__(256) void k_agg1_init(const float* __restrict__ h, const float* __restrict__ dinv,
                                                   float* __restrict__ o1, int total) {
    int i = blockIdx.x * 256 + threadIdx.x;
    if (i < total) {
        float dv = dinv[i >> 6];
        o1[i] = h[i] * dv * dv;  // self-loop contribution
    }
}

__global__ __launch_bounds__(256) void k_agg1_edges(const int* __restrict__ src, const int* __restrict__ dst,
                                                    const float* __restrict__ nrm, const float* __restrict__ h,
                                                    float* o1, int E) {
    int gid = blockIdx.x * 256 + threadIdx.x;
    int e = gid >> 6;
    if (e >= E) return;
    int f = gid & 63;
    float v = h[(size_t)src[e] * NHID + f] * nrm[e];
    atomicAdd(&o1[(size_t)dst[e] * NHID + f], v);
}

// ---------------- GEMM2: h2 = relu(o1 + b1) @ W2  [N,64]x[64,21] ----------------
// Block = 128 threads, one row per thread; rows staged relu'd in LDS with
// stride 65 (bank = (tid+k)%32 -> 2-way, free). W2 (5.3KB) in LDS, broadcast.

__global__ __launch_bounds__(128) void k_gemm2(const float* __restrict__ o1, const float* __restrict__ W2,
                                               const float* __restrict__ b1, float* __restrict__ h2, int N) {
    __shared__ float rs[128 * 65];      // 33.3 KB
    __shared__ float Ws[NHID * NOUT];   // 5.3 KB
    int tid = threadIdx.x;
    for (int i = tid; i < NHID * NOUT; i += 128) Ws[i] = W2[i];
    int base = blockIdx.x * 128;
#pragma unroll
    for (int i = 0; i < 16; ++i) {
        int idx = tid + i * 128;
        int row = idx >> 4;
        int f4 = (idx & 15) * 4;
        int grow = base + row;
        float4 v = make_float4(0.f, 0.f, 0.f, 0.f);
        if (grow < N) v = *(const float4*)&o1[(size_t)grow * NHID + f4];
        float4 bb = *(const float4*)&b1[f4];
        float* d = &rs[row * 65 + f4];
        d[0] = fmaxf(v.x + bb.x, 0.f);
        d[1] = fmaxf(v.y + bb.y, 0.f);
        d[2] = fmaxf(v.z + bb.z, 0.f);
        d[3] = fmaxf(v.w + bb.w, 0.f);
    }
    __syncthreads();
    int row = base + tid;
    if (row >= N) return;
    float acc[NOUT];
#pragma unroll
    for (int j = 0; j < NOUT; ++j) acc[j] = 0.f;
    for (int k = 0; k < NHID; ++k) {
        float av = rs[tid * 65 + k];
#pragma unroll
        for (int j = 0; j < NOUT; ++j) acc[j] = fmaf(av, Ws[k * NOUT + j], acc[j]);
    }
    float* outp = &h2[(size_t)row * NOUT];
#pragma unroll
    for (int j = 0; j < NOUT; ++j) outp[j] = acc[j];
}

// ---------------- aggregation layer 2 (21 feat) + bias ----------------

__global__ __launch_bounds__(256) void k_agg2_init(const float* __restrict__ h2, const float* __restrict__ dinv,
                                                   const float* __restrict__ b2, float* __restrict__ out, int N) {
    int i = blockIdx.x * 256 + threadIdx.x;
    if (i >= N * NOUT) return;
    int n = i / NOUT;
    int c = i - n * NOUT;
    float dv = dinv[n];
    out[i] = b2[c] + h2[i] * dv * dv;  // bias + self-loop
}

__global__ __launch_bounds__(256) void k_agg2_edges(const int* __restrict__ src, const int* __restrict__ dst,
                                                    const float* __restrict__ nrm, const float* __restrict__ h2,
                                                    float* out, int E) {
    int gid = blockIdx.x * 256 + threadIdx.x;
    int e = gid / NOUT;
    if (e >= E) return;
    int f = gid - e * NOUT;
    float v = h2[(size_t)src[e] * NOUT + f] * nrm[e];
    atomicAdd(&out[(size_t)dst[e] * NOUT + f], v);
}

// ---------------- launch ----------------

extern "C" void kernel_launch(void* const* d_in, const int* in_sizes, int n_in,
                              void* d_out, int out_size, void* d_ws, size_t ws_size,
                              hipStream_t stream) {
    const float* x  = (const float*)d_in[0];
    const int*   ei = (const int*)d_in[1];
    const float* W1 = (const float*)d_in[2];
    const float* b1 = (const float*)d_in[3];
    const float* W2 = (const float*)d_in[4];
    const float* b2 = (const float*)d_in[5];
    float* out = (float*)d_out;

    int N = in_sizes[0] / NFEAT;
    int E = in_sizes[1] / 2;
    const int* src = ei;
    const int* dst = ei + E;

    // workspace layout (floats), all offsets 256B-aligned
    size_t Npad = ((size_t)N + 63) & ~(size_t)63;
    size_t Epad = ((size_t)E + 63) & ~(size_t)63;
    float* deg = (float*)d_ws;                 // N   (holds dinv after k_dinv)
    float* nrm = deg + Npad;                   // E
    float* h   = nrm + Epad;                   // N*64
    float* o1  = h + (size_t)N * NHID;         // N*64
    float* h2  = o1 + (size_t)N * NHID;        // N*21

    const int B = 256;
    k_deg_init <<<(N + B - 1) / B, B, 0, stream>>>(deg, N);
    k_deg_edges<<<(E + B - 1) / B, B, 0, stream>>>(dst, deg, E);
    k_dinv     <<<(N + B - 1) / B, B, 0, stream>>>(deg, N);
    k_norm     <<<(E + B - 1) / B, B, 0, stream>>>(src, dst, deg, nrm, E);

    k_gemm1    <<<(N + 63) / 64, 256, 0, stream>>>(x, W1, h, N);

    long long t1 = (long long)N * NHID;
    k_agg1_init <<<(int)((t1 + B - 1) / B), B, 0, stream>>>(h, deg, o1, (int)t1);
    long long e1 = (long long)E * NHID;
    k_agg1_edges<<<(int)((e1 + B - 1) / B), B, 0, stream>>>(src, dst, nrm, h, o1, E);

    k_gemm2    <<<(N + 127) / 128, 128, 0, stream>>>(o1, W2, b1, h2, N);

    long long t2 = (long long)N * NOUT;
    k_agg2_init <<<(int)((t2 + B - 1) / B), B, 0, stream>>>(h2, deg, b2, out, N);
    long long e2 = (long long)E * NOUT;
    k_agg2_edges<<<(int)((e2 + B - 1) / B), B, 0, stream>>>(src, dst, nrm, h2, out, E);
}

// Round 2
// 350.681 us; speedup vs baseline: 2.0873x; 2.0873x over previous
//
#include <hip/hip_runtime.h>

#define NFEAT 128
#define NHID  64
#define NOUT  21

// ================= CSR build (counting sort by dst) =================

__global__ __launch_bounds__(256) void k_count(const int* __restrict__ dst, int* cnt, int E) {
    int e = blockIdx.x * 256 + threadIdx.x;
    if (e < E) atomicAdd(&cnt[dst[e]], 1);
}

__global__ __launch_bounds__(256) void k_dinv(const int* __restrict__ cnt, float* __restrict__ dinv, int N) {
    int i = blockIdx.x * 256 + threadIdx.x;
    if (i < N) dinv[i] = rsqrtf((float)(cnt[i] + 1));  // +1 self-loop
}

// exclusive scan of cnt[N] -> rowptr[N]; rowptr[N]=E set in scan3.
__global__ __launch_bounds__(256) void k_scan1(const int* __restrict__ cnt, int* __restrict__ rowptr,
                                               int* __restrict__ bsum, int N) {
    __shared__ int sh[256];
    int tid = threadIdx.x;
    int base = blockIdx.x * 1024 + tid * 4;
    int v[4]; int s = 0;
#pragma unroll
    for (int j = 0; j < 4; ++j) { v[j] = (base + j < N) ? cnt[base + j] : 0; s += v[j]; }
    sh[tid] = s; __syncthreads();
    for (int off = 1; off < 256; off <<= 1) {          // Hillis-Steele inclusive
        int t = (tid >= off) ? sh[tid - off] : 0;
        __syncthreads();
        sh[tid] += t;
        __syncthreads();
    }
    int run = sh[tid] - s;                              // exclusive prefix in block
#pragma unroll
    for (int j = 0; j < 4; ++j) { if (base + j < N) rowptr[base + j] = run; run += v[j]; }
    if (tid == 255) bsum[blockIdx.x] = sh[255];
}

__global__ __launch_bounds__(128) void k_scan2(int* bsum, int nb) {
    __shared__ int sh[128];
    int tid = threadIdx.x;
    int v = (tid < nb) ? bsum[tid] : 0;
    sh[tid] = v; __syncthreads();
    for (int off = 1; off < 128; off <<= 1) {
        int t = (tid >= off) ? sh[tid - off] : 0;
        __syncthreads();
        sh[tid] += t;
        __syncthreads();
    }
    if (tid < nb) bsum[tid] = sh[tid] - v;              // exclusive
}

__global__ __launch_bounds__(256) void k_scan3(int* rowptr, const int* __restrict__ bsum, int N, int E) {
    int tid = threadIdx.x;
    int base = blockIdx.x * 1024 + tid * 4;
    int add = bsum[blockIdx.x];
#pragma unroll
    for (int j = 0; j < 4; ++j) if (base + j < N) rowptr[base + j] += add;
    if (blockIdx.x == 0 && tid == 0) rowptr[N] = E;
}

// scatter edges into dst-sorted order; pack (src, norm) into int2 for one 8B broadcast load.
__global__ __launch_bounds__(256) void k_scatter(const int* __restrict__ src, const int* __restrict__ dst,
                                                 const int* __restrict__ rowptr, int* __restrict__ fill,
                                                 const float* __restrict__ dinv, int2* __restrict__ edata, int E) {
    int e = blockIdx.x * 256 + threadIdx.x;
    if (e >= E) return;
    int d = dst[e], s = src[e];
    int pos = rowptr[d] + atomicAdd(&fill[d], 1);
    int2 ed; ed.x = s; ed.y = __float_as_int(dinv[s] * dinv[d]);
    edata[pos] = ed;
}

// ================= GEMM1: h = x @ W1  [N,128]x[128,64] =================

__global__ __launch_bounds__(256) void k_gemm1(const float* __restrict__ x, const float* __restrict__ W1,
                                               float* __restrict__ h, int N) {
    __shared__ float Ws[NFEAT * NHID];  // 32 KB
    int tid = threadIdx.x;
#pragma unroll
    for (int i = 0; i < 8; ++i) {
        int idx = (tid + i * 256) * 4;
        *(float4*)&Ws[idx] = *(const float4*)&W1[idx];
    }
    __syncthreads();
    int row = blockIdx.x * 64 + (tid >> 2);
    if (row >= N) return;
    int cg = (tid & 3) * 16;
    float acc[16];
#pragma unroll
    for (int j = 0; j < 16; ++j) acc[j] = 0.f;
    const float* xr = x + (size_t)row * NFEAT;
#pragma unroll 4
    for (int k4 = 0; k4 < NFEAT / 4; ++k4) {
        float4 xv = *(const float4*)&xr[k4 * 4];
        float xs[4] = {xv.x, xv.y, xv.z, xv.w};
#pragma unroll
        for (int kk = 0; kk < 4; ++kk) {
            const float* wrow = &Ws[(k4 * 4 + kk) * NHID + cg];
#pragma unroll
            for (int j4 = 0; j4 < 4; ++j4) {
                float4 w = *(const float4*)&wrow[j4 * 4];
                acc[j4 * 4 + 0] = fmaf(xs[kk], w.x, acc[j4 * 4 + 0]);
                acc[j4 * 4 + 1] = fmaf(xs[kk], w.y, acc[j4 * 4 + 1]);
                acc[j4 * 4 + 2] = fmaf(xs[kk], w.z, acc[j4 * 4 + 2]);
                acc[j4 * 4 + 3] = fmaf(xs[kk], w.w, acc[j4 * 4 + 3]);
            }
        }
    }
    float* hr = h + (size_t)row * NHID + cg;
#pragma unroll
    for (int j4 = 0; j4 < 4; ++j4)
        *(float4*)&hr[j4 * 4] = make_float4(acc[j4 * 4 + 0], acc[j4 * 4 + 1],
                                            acc[j4 * 4 + 2], acc[j4 * 4 + 3]);
}

// ===== aggregation layer 1: one wave per dst node, 64 lanes = 64 feats =====
// o1[n,:] = relu( b1 + dv^2*h[n,:] + sum_e nrm_e * h[src_e,:] )

__global__ __launch_bounds__(256) void k_agg1(const int* __restrict__ rowptr, const int2* __restrict__ edata,
                                              const float* __restrict__ h, const float* __restrict__ dinv,
                                              const float* __restrict__ b1, float* __restrict__ o1, int N) {
    int tid = threadIdx.x;
    int node = blockIdx.x * 4 + (tid >> 6);
    if (node >= N) return;
    int f = tid & 63;
    float dv = dinv[node];
    float acc = h[(size_t)node * NHID + f] * dv * dv;   // self-loop
    int i = rowptr[node], end = rowptr[node + 1];
    for (; i + 1 < end; i += 2) {
        int2 e0 = edata[i], e1 = edata[i + 1];
        float h0 = h[(size_t)e0.x * NHID + f];
        float h1 = h[(size_t)e1.x * NHID + f];
        acc = fmaf(__int_as_float(e0.y), h0, acc);
        acc = fmaf(__int_as_float(e1.y), h1, acc);
    }
    if (i < end) {
        int2 e0 = edata[i];
        acc = fmaf(__int_as_float(e0.y), h[(size_t)e0.x * NHID + f], acc);
    }
    o1[(size_t)node * NHID + f] = fmaxf(acc + b1[f], 0.f);  // fused +b1, relu
}

// ===== GEMM2: h2 = o1 @ W2  [N,64]x[64,21] (o1 already relu'd+biased) =====

__global__ __launch_bounds__(128) void k_gemm2(const float* __restrict__ o1, const float* __restrict__ W2,
                                               float* __restrict__ h2, int N) {
    __shared__ float rs[128 * 65];      // 33.3 KB, stride 65 kills conflicts
    __shared__ float Ws[NHID * NOUT];   // 5.3 KB
    int tid = threadIdx.x;
    for (int i = tid; i < NHID * NOUT; i += 128) Ws[i] = W2[i];
    int base = blockIdx.x * 128;
#pragma unroll
    for (int i = 0; i < 16; ++i) {
        int idx = tid + i * 128;
        int row = idx >> 4;
        int f4 = (idx & 15) * 4;
        int grow = base + row;
        float4 v = make_float4(0.f, 0.f, 0.f, 0.f);
        if (grow < N) v = *(const float4*)&o1[(size_t)grow * NHID + f4];
        float* d = &rs[row * 65 + f4];
        d[0] = v.x; d[1] = v.y; d[2] = v.z; d[3] = v.w;
    }
    __syncthreads();
    int row = base + tid;
    if (row >= N) return;
    float acc[NOUT];
#pragma unroll
    for (int j = 0; j < NOUT; ++j) acc[j] = 0.f;
    for (int k = 0; k < NHID; ++k) {
        float av = rs[tid * 65 + k];
#pragma unroll
        for (int j = 0; j < NOUT; ++j) acc[j] = fmaf(av, Ws[k * NOUT + j], acc[j]);
    }
    float* outp = &h2[(size_t)row * NOUT];
#pragma unroll
    for (int j = 0; j < NOUT; ++j) outp[j] = acc[j];
}

// ===== aggregation layer 2: 8 threads/node (7 active x 3 feats = 21) =====
// out[n,:] = b2 + dv^2*h2[n,:] + sum_e nrm_e * h2[src_e,:]

__global__ __launch_bounds__(256) void k_agg2(const int* __restrict__ rowptr, const int2* __restrict__ edata,
                                              const float* __restrict__ h2, const float* __restrict__ dinv,
                                              const float* __restrict__ b2, float* __restrict__ out, int N) {
    int tid = threadIdx.x;
    int node = blockIdx.x * 32 + (tid >> 3);
    if (node >= N) return;
    int t = tid & 7;
    if (t >= 7) return;
    int c0 = t * 3;
    float dv = dinv[node];
    size_t nb = (size_t)node * NOUT;
    float dv2 = dv * dv;
    float a0 = h2[nb + c0] * dv2;
    float a1 = h2[nb + c0 + 1] * dv2;
    float a2 = h2[nb + c0 + 2] * dv2;
    int i = rowptr[node], end = rowptr[node + 1];
    for (; i + 1 < end; i += 2) {
        int2 e0 = edata[i], e1 = edata[i + 1];
        float w0 = __int_as_float(e0.y), w1 = __int_as_float(e1.y);
        size_t p0 = (size_t)e0.x * NOUT + c0, p1 = (size_t)e1.x * NOUT + c0;
        float x00 = h2[p0], x01 = h2[p0 + 1], x02 = h2[p0 + 2];
        float x10 = h2[p1], x11 = h2[p1 + 1], x12 = h2[p1 + 2];
        a0 = fmaf(w0, x00, a0); a1 = fmaf(w0, x01, a1); a2 = fmaf(w0, x02, a2);
        a0 = fmaf(w1, x10, a0); a1 = fmaf(w1, x11, a1); a2 = fmaf(w1, x12, a2);
    }
    if (i < end) {
        int2 e0 = edata[i];
        float w = __int_as_float(e0.y);
        size_t p = (size_t)e0.x * NOUT + c0;
        a0 = fmaf(w, h2[p], a0); a1 = fmaf(w, h2[p + 1], a1); a2 = fmaf(w, h2[p + 2], a2);
    }
    out[nb + c0]     = a0 + b2[c0];
    out[nb + c0 + 1] = a1 + b2[c0 + 1];
    out[nb + c0 + 2] = a2 + b2[c0 + 2];
}

// ================= launch =================

extern "C" void kernel_launch(void* const* d_in, const int* in_sizes, int n_in,
                              void* d_out, int out_size, void* d_ws, size_t ws_size,
                              hipStream_t stream) {
    const float* x  = (const float*)d_in[0];
    const int*   ei = (const int*)d_in[1];
    const float* W1 = (const float*)d_in[2];
    const float* b1 = (const float*)d_in[3];
    const float* W2 = (const float*)d_in[4];
    const float* b2 = (const float*)d_in[5];
    float* out = (float*)d_out;

    int N = in_sizes[0] / NFEAT;
    int E = in_sizes[1] / 2;
    const int* src = ei;
    const int* dst = ei + E;

    // workspace carve-out (256B-aligned)
    char* p = (char*)d_ws;
    auto alloc = [&](size_t bytes) { void* r = (void*)p; p += (bytes + 255) & ~(size_t)255; return r; };
    int*   cnt    = (int*)alloc((size_t)N * 4);          // histogram, then fill counter
    int*   rowptr = (int*)alloc((size_t)(N + 1) * 4);
    int*   bsum   = (int*)alloc(128 * 4);
    int2*  edata  = (int2*)alloc((size_t)E * 8);         // (src, norm) dst-sorted
    float* dinv   = (float*)alloc((size_t)N * 4);
    float* h      = (float*)alloc((size_t)N * NHID * 4);
    float* o1     = (float*)alloc((size_t)N * NHID * 4);
    float* h2     = (float*)alloc((size_t)N * NOUT * 4);

    const int B = 256;
    int nb = (N + 1023) / 1024;

    hipMemsetAsync(cnt, 0, (size_t)N * 4, stream);
    k_count  <<<(E + B - 1) / B, B, 0, stream>>>(dst, cnt, E);
    k_dinv   <<<(N + B - 1) / B, B, 0, stream>>>(cnt, dinv, N);
    k_scan1  <<<nb, 256, 0, stream>>>(cnt, rowptr, bsum, N);
    k_scan2  <<<1, 128, 0, stream>>>(bsum, nb);
    k_scan3  <<<nb, 256, 0, stream>>>(rowptr, bsum, N, E);
    hipMemsetAsync(cnt, 0, (size_t)N * 4, stream);
    k_scatter<<<(E + B - 1) / B, B, 0, stream>>>(src, dst, rowptr, cnt, dinv, edata, E);

    k_gemm1  <<<(N + 63) / 64, 256, 0, stream>>>(x, W1, h, N);
    k_agg1   <<<(N + 3) / 4, 256, 0, stream>>>(rowptr, edata, h, dinv, b1, o1, N);
    k_gemm2  <<<(N + 127) / 128, 128, 0, stream>>>(o1, W2, h2, N);
    k_agg2   <<<(N + 31) / 32, 256, 0, stream>>>(rowptr, edata, h2, dinv, b2, out, N);
}